// Round 8
// baseline (234.854 us; speedup 1.0000x reference)
//
#include <hip/hip_runtime.h>
#include <hip/hip_bf16.h>

// Problem constants
constexpr int B  = 4;
constexpr int E  = 1024;
constexpr int Wn = 2048;
constexpr int H  = 16;
constexpr int Dh = 64;   // E / H

typedef short bf16x8 __attribute__((ext_vector_type(8)));
typedef float f32x4  __attribute__((ext_vector_type(4)));

__device__ inline unsigned short f2bf(float f){
    unsigned int u = __builtin_bit_cast(unsigned int, f);
    u = (u + 0x7fffu + ((u >> 16) & 1u)) >> 16;   // RNE
    return (unsigned short)u;
}
__device__ inline float bf2f(unsigned short u){
    return __builtin_bit_cast(float, (unsigned int)u << 16);
}
__device__ inline unsigned int pack_bf16_trunc(float lo, float hi){
    return __builtin_amdgcn_perm(__builtin_bit_cast(unsigned int, hi),
                                 __builtin_bit_cast(unsigned int, lo), 0x07060302u);
}
__device__ inline float exp2_fast(float x){ return __builtin_amdgcn_exp2f(x); }

// ---------------------------------------------------------------------------
// K0: x -> xdi (bf16, columns permuted inside each 32-block for single-MFMA PV)
// ---------------------------------------------------------------------------
__global__ void k_vint(const float* __restrict__ x, unsigned short* __restrict__ xdi){
    int tid = blockIdx.x*256 + threadIdx.x;     // [row(12) | g(8)]
    int g   = tid & 255;
    int row = tid >> 8;
    int kgw = g & 3;
    int kv0 = (g >> 2) << 5;
    const float* src = x + (size_t)row*Wn + kv0 + 4*kgw;
    float4 a = *reinterpret_cast<const float4*>(src);
    float4 b = *reinterpret_cast<const float4*>(src + 16);
    union { unsigned short us[8]; uint4 v; } u;
    u.us[0]=f2bf(a.x); u.us[1]=f2bf(a.y); u.us[2]=f2bf(a.z); u.us[3]=f2bf(a.w);
    u.us[4]=f2bf(b.x); u.us[5]=f2bf(b.y); u.us[6]=f2bf(b.z); u.us[7]=f2bf(b.w);
    *reinterpret_cast<uint4*>(xdi + (size_t)row*Wn + kv0 + 8*kgw) = u.v;
}

// ---------------------------------------------------------------------------
// K1: x -> xT (K operand, unscaled) and xQ (Q operand, scaled E^-0.5*log2e)
// ---------------------------------------------------------------------------
__global__ void k_xT(const float* __restrict__ x, unsigned short* __restrict__ xT,
                     unsigned short* __restrict__ xQ){
    const float qs = 0.03125f * 1.44269504088896340736f;
    int tid = blockIdx.x*256 + threadIdx.x;
    int w   = tid & (Wn-1);
    int dg  = (tid >> 11) & 7;
    int bh  = tid >> 14;
    const float* src = x + ((size_t)bh*Dh + dg*8)*Wn + w;
    union { unsigned short us[8]; uint4 v; } u, uq;
    #pragma unroll
    for (int i = 0; i < 8; i++){
        float f = src[(size_t)i*Wn];
        u.us[i]  = f2bf(f);
        uq.us[i] = f2bf(f * qs);
    }
    size_t off = ((size_t)bh*Wn + w)*Dh + dg*8;
    *reinterpret_cast<uint4*>(xT + off) = u.v;
    *reinterpret_cast<uint4*>(xQ + off) = uq.v;
}

// ---------------------------------------------------------------------------
// K2: M_d -> MT (bf16 transposed)
// ---------------------------------------------------------------------------
__global__ void k_MT(const float* __restrict__ M, unsigned short* __restrict__ MT){
    int tid = blockIdx.x*256 + threadIdx.x;  // [eg(7) | f(10)]
    int f  = tid & (E-1);
    int eg = tid >> 10;
    union { unsigned short us[8]; uint4 v; } u;
    #pragma unroll
    for (int i = 0; i < 8; i++) u.us[i] = f2bf(M[(size_t)(eg*8+i)*E + f]);
    *reinterpret_cast<uint4*>(MT + (size_t)f*E + eg*8) = u.v;
}

// ---------------------------------------------------------------------------
// K3: flash attention, no max-tracking, KV-split heavy blocks (additive
// partials). Register ping-pong prefetch with:
//  - __launch_bounds__(256,2): VGPR cap 256 so BOTH in-flight KV frag sets
//    stay allocated (r7's cap of ~80 made the compiler sink the loads).
//  - pointer-increment addressing (1 K ptr + 4 V ptrs, constant strides,
//    static load offsets) -> ~12 VALU/step of addressing.
//  - l accumulated by an extra MFMA with ones-A-fragment (no VALU adds,
//    no epilogue shuffles: every lane's C holds its column sum).
//  - interior steps mask-free; the final prefetch IS the diagonal tile.
// ---------------------------------------------------------------------------
struct KVf { bf16x8 k0a, k0b, k1a, k1b, v0, v1, v2, v3; };

__global__ __launch_bounds__(256, 2) void k_attn(const unsigned short* __restrict__ xT,
                                                 const unsigned short* __restrict__ xQ,
                                                 const unsigned short* __restrict__ xdi,
                                                 unsigned short* __restrict__ tws,
                                                 unsigned short* __restrict__ pacc,
                                                 float* __restrict__ pl){
    const int lane = threadIdx.x & 63;
    const int wv   = threadIdx.x >> 6;
    const int jl = lane & 15, kg = lane >> 4;
    const int bid = blockIdx.x >> 4;                // 0..95
    const int hg  = blockIdx.x & 15;
    const int bh  = hg*4 + wv;

    int qb, kvb, kve, half;
    bool diag, heavy;
    if (bid < 32){
        qb = 32 + bid; kvb = 0; kve = 1024; diag = false; heavy = true; half = 0;
    } else {
        int k = (bid - 32) >> 1;
        if (bid & 1){ qb = 31 - k; kvb = 0;    kve = qb*32; diag = true; heavy = false; half = 0; }
        else        { qb = 63 - k; kvb = 1024; kve = qb*32; diag = true; heavy = true;  half = 1; }
    }
    const int q0 = qb*32;
    const int steps = (kve - kvb) >> 5;             // interior step count

    const bf16x8* xQr = reinterpret_cast<const bf16x8*>(xQ + (size_t)bh*Wn*Dh);

    bf16x8 bq[2][2];
    #pragma unroll
    for (int jt = 0; jt < 2; jt++){
        bq[jt][0] = xQr[(q0+jt*16+jl)*8 + kg];
        bq[jt][1] = xQr[(q0+jt*16+jl)*8 + 4 + kg];
    }

    // ones A-fragment for the l-sum MFMA
    union { bf16x8 v; unsigned short us[8]; } ones;
    #pragma unroll
    for (int i = 0; i < 8; i++) ones.us[i] = 0x3F80;

    f32x4 acc[2][4] = {};
    f32x4 accl[2] = {};

    // ---- pointer setup (byte pointers, constant strides)
    const char* pK  = (const char*)xT  + (((size_t)bh*Wn + kvb + jl)*Dh + kg*8)*2;
    const char* pV0 = (const char*)xdi + (((size_t)bh*Dh +  0 + jl)*Wn + kvb + kg*8)*2;
    const char* pV1 = (const char*)xdi + (((size_t)bh*Dh + 16 + jl)*Wn + kvb + kg*8)*2;
    const char* pV2 = (const char*)xdi + (((size_t)bh*Dh + 32 + jl)*Wn + kvb + kg*8)*2;
    const char* pV3 = (const char*)xdi + (((size_t)bh*Dh + 48 + jl)*Wn + kvb + kg*8)*2;

    auto LOAD = [&]() -> KVf {
        KVf f;
        f.k0a = *reinterpret_cast<const bf16x8*>(pK);
        f.k0b = *reinterpret_cast<const bf16x8*>(pK + 64);
        f.k1a = *reinterpret_cast<const bf16x8*>(pK + 2048);
        f.k1b = *reinterpret_cast<const bf16x8*>(pK + 2112);
        f.v0  = *reinterpret_cast<const bf16x8*>(pV0);
        f.v1  = *reinterpret_cast<const bf16x8*>(pV1);
        f.v2  = *reinterpret_cast<const bf16x8*>(pV2);
        f.v3  = *reinterpret_cast<const bf16x8*>(pV3);
        pK += 4096; pV0 += 64; pV1 += 64; pV2 += 64; pV3 += 64;
        return f;
    };

    auto compute = [&](const KVf& f){
        #pragma unroll
        for (int jt = 0; jt < 2; jt++){
            f32x4 s0 = {0,0,0,0}, s1 = {0,0,0,0};
            s0 = __builtin_amdgcn_mfma_f32_16x16x32_bf16(f.k0a, bq[jt][0], s0, 0,0,0);
            s0 = __builtin_amdgcn_mfma_f32_16x16x32_bf16(f.k0b, bq[jt][1], s0, 0,0,0);
            s1 = __builtin_amdgcn_mfma_f32_16x16x32_bf16(f.k1a, bq[jt][0], s1, 0,0,0);
            s1 = __builtin_amdgcn_mfma_f32_16x16x32_bf16(f.k1b, bq[jt][1], s1, 0,0,0);

            union { bf16x8 v; unsigned int w[4]; } bp;
            bp.w[0] = pack_bf16_trunc(exp2_fast(s0[0]), exp2_fast(s0[1]));
            bp.w[1] = pack_bf16_trunc(exp2_fast(s0[2]), exp2_fast(s0[3]));
            bp.w[2] = pack_bf16_trunc(exp2_fast(s1[0]), exp2_fast(s1[1]));
            bp.w[3] = pack_bf16_trunc(exp2_fast(s1[2]), exp2_fast(s1[3]));

            accl[jt]   = __builtin_amdgcn_mfma_f32_16x16x32_bf16(ones.v, bp.v, accl[jt], 0,0,0);
            acc[jt][0] = __builtin_amdgcn_mfma_f32_16x16x32_bf16(f.v0, bp.v, acc[jt][0], 0,0,0);
            acc[jt][1] = __builtin_amdgcn_mfma_f32_16x16x32_bf16(f.v1, bp.v, acc[jt][1], 0,0,0);
            acc[jt][2] = __builtin_amdgcn_mfma_f32_16x16x32_bf16(f.v2, bp.v, acc[jt][2], 0,0,0);
            acc[jt][3] = __builtin_amdgcn_mfma_f32_16x16x32_bf16(f.v3, bp.v, acc[jt][3], 0,0,0);
        }
    };

    auto compute_diag = [&](const KVf& f){
        #pragma unroll
        for (int jt = 0; jt < 2; jt++){
            f32x4 s0 = {0,0,0,0}, s1 = {0,0,0,0};
            s0 = __builtin_amdgcn_mfma_f32_16x16x32_bf16(f.k0a, bq[jt][0], s0, 0,0,0);
            s0 = __builtin_amdgcn_mfma_f32_16x16x32_bf16(f.k0b, bq[jt][1], s0, 0,0,0);
            s1 = __builtin_amdgcn_mfma_f32_16x16x32_bf16(f.k1a, bq[jt][0], s1, 0,0,0);
            s1 = __builtin_amdgcn_mfma_f32_16x16x32_bf16(f.k1b, bq[jt][1], s1, 0,0,0);

            const int lim = 16*jt + jl;
            float p[8];
            #pragma unroll
            for (int r = 0; r < 4; r++){
                int c = 4*kg + r;
                p[r]   = (c      <= lim) ? exp2_fast(s0[r]) : 0.f;
                p[4+r] = (c + 16 <= lim) ? exp2_fast(s1[r]) : 0.f;
            }
            union { bf16x8 v; unsigned int w[4]; } bp;
            bp.w[0] = pack_bf16_trunc(p[0], p[1]);
            bp.w[1] = pack_bf16_trunc(p[2], p[3]);
            bp.w[2] = pack_bf16_trunc(p[4], p[5]);
            bp.w[3] = pack_bf16_trunc(p[6], p[7]);

            accl[jt]   = __builtin_amdgcn_mfma_f32_16x16x32_bf16(ones.v, bp.v, accl[jt], 0,0,0);
            acc[jt][0] = __builtin_amdgcn_mfma_f32_16x16x32_bf16(f.v0, bp.v, acc[jt][0], 0,0,0);
            acc[jt][1] = __builtin_amdgcn_mfma_f32_16x16x32_bf16(f.v1, bp.v, acc[jt][1], 0,0,0);
            acc[jt][2] = __builtin_amdgcn_mfma_f32_16x16x32_bf16(f.v2, bp.v, acc[jt][2], 0,0,0);
            acc[jt][3] = __builtin_amdgcn_mfma_f32_16x16x32_bf16(f.v3, bp.v, acc[jt][3], 0,0,0);
        }
    };

    // ---- ping-pong main loop: loads run exactly one step ahead; the final
    // prefetch lands on the diagonal tile.
    {
        KVf a = LOAD();
        if (steps & 1){
            KVf b = LOAD();
            compute(a);
            a = b;
        }
        const int pairs = steps >> 1;
        for (int i = 0; i < pairs; ++i){
            KVf b = LOAD();
            compute(a);
            a = LOAD();
            compute(b);
        }
        if (diag) compute_diag(a);
    }

    if (!heavy){
        // ---- light epilogue: normalize (accl holds column sums), write tws
        #pragma unroll
        for (int jt = 0; jt < 2; jt++){
            const float inv = 1.0f / accl[jt][0];
            unsigned short* trow = tws + ((size_t)(bh >> 4)*Wn + q0 + jt*16 + jl)*E + (bh & 15)*Dh;
            #pragma unroll
            for (int dt = 0; dt < 4; dt++){
                union { unsigned short us[4]; ushort4 v; } o;
                #pragma unroll
                for (int r = 0; r < 4; r++) o.us[r] = f2bf(acc[jt][dt][r] * inv);
                *reinterpret_cast<ushort4*>(trow + dt*16 + 4*kg) = o.v;
            }
        }
    } else {
        // ---- heavy epilogue: write bf16 acc partial + f32 l partial
        const int qh = qb - 32;
        const size_t slot = (size_t)(bh*32 + qh)*2 + half;
        if (kg == 0){
            pl[slot*32 + jl]      = accl[0][0];
            pl[slot*32 + 16 + jl] = accl[1][0];
        }
        unsigned short* pa = pacc + slot*2048;
        #pragma unroll
        for (int jt = 0; jt < 2; jt++){
            #pragma unroll
            for (int dt = 0; dt < 4; dt++){
                union { unsigned short us[4]; ushort4 v; } o;
                #pragma unroll
                for (int r = 0; r < 4; r++) o.us[r] = f2bf(acc[jt][dt][r]);
                *reinterpret_cast<ushort4*>(pa + (jt*16+jl)*64 + dt*16 + 4*kg) = o.v;
            }
        }
    }
}

// ---------------------------------------------------------------------------
// K3b: combine the two KV-chunk partials of each heavy q-block, normalize,
// write tws. 2048 tiles; block=256 handles 4 tiles (64 thr/tile).
// ---------------------------------------------------------------------------
__global__ __launch_bounds__(256) void k_reduce(const unsigned short* __restrict__ pacc,
                                                const float* __restrict__ pl,
                                                unsigned short* __restrict__ tws){
    const int g  = blockIdx.x*4 + (threadIdx.x >> 6);   // tile 0..2047
    const int t  = threadIdx.x & 63;
    const int bh = g >> 5, qh = g & 31;
    const int q  = t >> 1;
    const int dbase = (t & 1)*32;
    const size_t slot0 = (size_t)(bh*32 + qh)*2;

    const float inv = 1.0f / (pl[slot0*32 + q] + pl[(slot0+1)*32 + q]);
    const unsigned short* a0 = pacc + slot0*2048 + q*64 + dbase;

    unsigned short* tw = tws + ((size_t)(bh >> 4)*Wn + (qh+32)*32 + q)*E + (bh & 15)*Dh + dbase;
    #pragma unroll
    for (int i = 0; i < 4; i++){
        union { uint4 v; unsigned short us[8]; } r0, r1, o;
        r0.v = *reinterpret_cast<const uint4*>(a0 + i*8);
        r1.v = *reinterpret_cast<const uint4*>(a0 + 2048 + i*8);
        #pragma unroll
        for (int j = 0; j < 8; j++)
            o.us[j] = f2bf((bf2f(r0.us[j]) + bf2f(r1.us[j])) * inv);
        *reinterpret_cast<uint4*>(tw + i*8) = o.v;
    }
}

// ---------------------------------------------------------------------------
// K4: out[b][f][w] = sum_e MT[f][e] * t_ws[b][w][e] + b_d[f]
// 128x128 C-tile per block (4 waves x 64x64); register ping-pong prefetch.
// ---------------------------------------------------------------------------
struct GF { bf16x8 am0, am1, am2, am3, bn0, bn1, bn2, bn3; };

__global__ __launch_bounds__(256, 2) void k_gemm(const unsigned short* __restrict__ MT,
                                                 const unsigned short* __restrict__ tws,
                                                 const float* __restrict__ bd,
                                                 float* __restrict__ out){
    const int lane = threadIdx.x & 63;
    const int wv   = threadIdx.x >> 6;
    const int jl = lane & 15, kg = lane >> 4;
    const int blk = blockIdx.x;
    const int b  = blk >> 7;          // 128 tiles per batch
    const int t2 = blk & 127;
    const int f0 = (t2 >> 4)*128 + (wv >> 1)*64;
    const int w0 = (t2 & 15)*128 + (wv &  1)*64;

    const char* pA = (const char*)MT + (((size_t)(f0 + jl))*E + kg*8)*2;
    const char* pB = (const char*)(tws + (size_t)b*Wn*E) + (((size_t)(w0 + jl))*E + kg*8)*2;

    auto LOAD = [&]() -> GF {
        GF g;
        g.am0 = *reinterpret_cast<const bf16x8*>(pA);
        g.am1 = *reinterpret_cast<const bf16x8*>(pA + 16*E*2);
        g.am2 = *reinterpret_cast<const bf16x8*>(pA + 32*E*2);
        g.am3 = *reinterpret_cast<const bf16x8*>(pA + 48*E*2);
        g.bn0 = *reinterpret_cast<const bf16x8*>(pB);
        g.bn1 = *reinterpret_cast<const bf16x8*>(pB + 16*E*2);
        g.bn2 = *reinterpret_cast<const bf16x8*>(pB + 32*E*2);
        g.bn3 = *reinterpret_cast<const bf16x8*>(pB + 48*E*2);
        pA += 64; pB += 64;
        return g;
    };

    f32x4 acc[4][4] = {};
    auto compute = [&](const GF& g){
        const bf16x8 am[4] = {g.am0, g.am1, g.am2, g.am3};
        const bf16x8 bn[4] = {g.bn0, g.bn1, g.bn2, g.bn3};
        #pragma unroll
        for (int i = 0; i < 4; i++)
            #pragma unroll
            for (int j = 0; j < 4; j++)
                acc[i][j] = __builtin_amdgcn_mfma_f32_16x16x32_bf16(am[i], bn[j], acc[i][j], 0,0,0);
    };

    {
        GF a = LOAD();                   // E/32 = 32 steps (even)
        for (int i = 0; i < 15; ++i){
            GF bb = LOAD();
            compute(a);
            a = LOAD();
            compute(bb);
        }
        GF bb = LOAD();
        compute(a);
        compute(bb);
    }

    #pragma unroll
    for (int i = 0; i < 4; i++){
        float bias[4];
        #pragma unroll
        for (int r = 0; r < 4; r++) bias[r] = bd[f0 + i*16 + 4*kg + r];
        #pragma unroll
        for (int j = 0; j < 4; j++){
            #pragma unroll
            for (int r = 0; r < 4; r++){
                out[((size_t)b*E + f0 + i*16 + 4*kg + r)*Wn + w0 + j*16 + jl]
                    = acc[i][j][r] + bias[r];
            }
        }
    }
}

// ---------------------------------------------------------------------------
extern "C" void kernel_launch(void* const* d_in, const int* in_sizes, int n_in,
                              void* d_out, int out_size, void* d_ws, size_t ws_size,
                              hipStream_t stream) {
    const float* x  = (const float*)d_in[0];   // (B,E,W)
    const float* Md = (const float*)d_in[1];   // (E,E)
    const float* bd = (const float*)d_in[2];   // (E,)
    float* out = (float*)d_out;                // (B,E,W)

    char* ws = (char*)d_ws;
    unsigned short* xT   = (unsigned short*)(ws);                    // 16 MB
    unsigned short* xQ   = (unsigned short*)(ws + (16u << 20));      // 16 MB
    unsigned short* xdi  = (unsigned short*)(ws + (32u << 20));      // 16 MB
    unsigned short* MT   = (unsigned short*)(ws + (48u << 20));      //  2 MB
    unsigned short* tws  = (unsigned short*)(ws + (50u << 20));      // 16 MB
    float*          pl   = (float*)(ws + (66u << 20));               // 512 KB
    unsigned short* pacc = (unsigned short*)(ws + (67u << 20));      // 16 MB

    hipLaunchKernelGGL(k_vint,   dim3(4096), dim3(256), 0, stream, x, xdi);
    hipLaunchKernelGGL(k_xT,     dim3(4096), dim3(256), 0, stream, x, xT, xQ);
    hipLaunchKernelGGL(k_MT,     dim3(512),  dim3(256), 0, stream, Md, MT);
    hipLaunchKernelGGL(k_attn,   dim3(96*16), dim3(256), 0, stream, xT, xQ, xdi, tws, pacc, pl);
    hipLaunchKernelGGL(k_reduce, dim3(512),  dim3(256), 0, stream, pacc, pl, tws);
    hipLaunchKernelGGL(k_gemm,   dim3(B*(E/128)*(Wn/128)), dim3(256), 0, stream, MT, tws, bd, out);
}